// Round 1
// baseline (3330.728 us; speedup 1.0000x reference)
//
#include <hip/hip_runtime.h>
#include <hip/hip_bf16.h>

// GCN encoder: h = relu(Agg(h @ W)) x3 after input linear.
// N=20000 nodes, E=640000 edges, H=128.
// ws layout: [dis: N floats][hA: N*128 floats][xw: N*128 floats]
// hA doubles as the agg buffer (h is dead once xw = h@W is computed).

#define HDIM 128

__global__ __launch_bounds__(256) void k_init_deg(float* __restrict__ deg, int N) {
    int i = blockIdx.x * 256 + threadIdx.x;
    if (i < N) deg[i] = 1.0f;  // self-loop contributes 1
}

__global__ __launch_bounds__(256) void k_count_deg(const int* __restrict__ dst,
                                                   float* __restrict__ deg, int E) {
    int e = blockIdx.x * 256 + threadIdx.x;
    if (e < E) atomicAdd(&deg[dst[e]], 1.0f);
}

__global__ __launch_bounds__(256) void k_deg_to_dis(float* __restrict__ deg, int N) {
    int i = blockIdx.x * 256 + threadIdx.x;
    if (i < N) deg[i] = rsqrtf(deg[i]);  // deg >= 1 always (self-loop)
}

// out[N,128] = A[N,128] @ W[128,128] (+ b). W staged in LDS (64KB).
// 8 rows per block, 32 threads/row, each thread computes 4 consecutive cols.
__global__ __launch_bounds__(256) void k_gemm(const float* __restrict__ A,
                                              const float* __restrict__ W,
                                              const float* __restrict__ b,
                                              float* __restrict__ out, int N) {
    __shared__ float Wl[HDIM * HDIM];
    __shared__ float Arow[8][HDIM];
    int tid = threadIdx.x;

    // stage W: 16384 floats = 4096 float4, 16 per thread, coalesced
    const float4* W4 = (const float4*)W;
    float4* Wl4 = (float4*)Wl;
    #pragma unroll
    for (int i = 0; i < 16; ++i) Wl4[tid + i * 256] = W4[tid + i * 256];

    int block_row = blockIdx.x * 8;
    {   // stage 8 A-rows: 1024 floats = 256 float4, 1 per thread
        int r = tid >> 5, c = (tid & 31) * 4;
        int row = block_row + r;
        float4 v = make_float4(0.f, 0.f, 0.f, 0.f);
        if (row < N) v = *(const float4*)(A + (long long)row * HDIM + c);
        *(float4*)(&Arow[r][c]) = v;
    }
    __syncthreads();

    int rl = tid >> 5;            // 0..7
    int f4 = (tid & 31) * 4;      // 0,4,...,124
    float4 acc = b ? *(const float4*)(b + f4) : make_float4(0.f, 0.f, 0.f, 0.f);
    #pragma unroll 8
    for (int k = 0; k < HDIM; ++k) {
        float a = Arow[rl][k];
        float4 w = *(const float4*)(&Wl[k * HDIM + f4]);
        acc.x += a * w.x; acc.y += a * w.y; acc.z += a * w.z; acc.w += a * w.w;
    }
    int row = block_row + rl;
    if (row < N) *(float4*)(out + (long long)row * HDIM + f4) = acc;
}

// agg[v] = b + xw[v] * dis[v]^2   (self-loop term + bias)
__global__ __launch_bounds__(256) void k_self_init(const float* __restrict__ xw,
                                                   const float* __restrict__ dis,
                                                   const float* __restrict__ b,
                                                   float* __restrict__ agg, int N) {
    int idx = blockIdx.x * 256 + threadIdx.x;
    int v = idx >> 5, q = idx & 31;
    if (v >= N) return;
    float dv = dis[v];
    float n = dv * dv;
    float4 m = *(const float4*)(xw + (long long)v * HDIM + q * 4);
    float4 bb = *(const float4*)(b + q * 4);
    float4 o;
    o.x = bb.x + m.x * n; o.y = bb.y + m.y * n;
    o.z = bb.z + m.z * n; o.w = bb.w + m.w * n;
    *(float4*)(agg + (long long)v * HDIM + q * 4) = o;
}

// per (edge, float4-chunk): agg[dst] += xw[src] * dis[src]*dis[dst]
__global__ __launch_bounds__(256) void k_edge_scatter(const int* __restrict__ src,
                                                      const int* __restrict__ dst,
                                                      const float* __restrict__ dis,
                                                      const float* __restrict__ xw,
                                                      float* __restrict__ agg, int E) {
    long long idx = (long long)blockIdx.x * 256 + threadIdx.x;
    int e = (int)(idx >> 5);
    if (e >= E) return;
    int q = (int)(idx & 31);
    int s = src[e], d = dst[e];
    float norm = dis[s] * dis[d];
    float4 m = *(const float4*)(xw + (long long)s * HDIM + q * 4);
    float* p = agg + (long long)d * HDIM + q * 4;
    atomicAdd(p + 0, m.x * norm);
    atomicAdd(p + 1, m.y * norm);
    atomicAdd(p + 2, m.z * norm);
    atomicAdd(p + 3, m.w * norm);
}

// out = max(in, 0)
__global__ __launch_bounds__(256) void k_relu(const float* __restrict__ in,
                                              float* __restrict__ out, long long n4) {
    long long i = (long long)blockIdx.x * 256 + threadIdx.x;
    if (i >= n4) return;
    float4 v = *(const float4*)(in + i * 4);
    float4 o;
    o.x = fmaxf(v.x, 0.f); o.y = fmaxf(v.y, 0.f);
    o.z = fmaxf(v.z, 0.f); o.w = fmaxf(v.w, 0.f);
    *(float4*)(out + i * 4) = o;
}

extern "C" void kernel_launch(void* const* d_in, const int* in_sizes, int n_in,
                              void* d_out, int out_size, void* d_ws, size_t ws_size,
                              hipStream_t stream) {
    const float* x    = (const float*)d_in[0];
    const int*   ei   = (const int*)d_in[1];   // [2, E]: first E = src, next E = dst
    const float* W_in = (const float*)d_in[2];
    const float* b_in = (const float*)d_in[3];
    const float* Ws   = (const float*)d_in[4]; // [3,128,128]
    const float* bs   = (const float*)d_in[5]; // [3,128]

    const int N = in_sizes[0] / HDIM;
    const int E = in_sizes[1] / 2;
    const int* src = ei;
    const int* dst = ei + E;

    float* dis = (float*)d_ws;                       // N floats
    float* hA  = dis + N;                            // N*128 floats (h / agg)
    float* xw  = hA + (long long)N * HDIM;           // N*128 floats

    int nb_N   = (N + 255) / 256;
    int nb_E   = (E + 255) / 256;
    int nb_NF4 = (N * 32 + 255) / 256;               // N*128/4 threads
    long long eth = (long long)E * 32;
    int nb_EF4 = (int)((eth + 255) / 256);
    int nb_gemm = (N + 7) / 8;
    long long n4 = (long long)N * HDIM / 4;
    int nb_n4 = (int)((n4 + 255) / 256);

    // degree -> dis
    k_init_deg<<<nb_N, 256, 0, stream>>>(dis, N);
    k_count_deg<<<nb_E, 256, 0, stream>>>(dst, dis, E);
    k_deg_to_dis<<<nb_N, 256, 0, stream>>>(dis, N);

    // h = x @ W_in + b_in
    k_gemm<<<nb_gemm, 256, 0, stream>>>(x, W_in, b_in, hA, N);

    for (int layer = 0; layer < 3; ++layer) {
        const float* W = Ws + (long long)layer * HDIM * HDIM;
        const float* b = bs + (long long)layer * HDIM;
        // xw = h @ W (no bias)
        k_gemm<<<nb_gemm, 256, 0, stream>>>(hA, W, nullptr, xw, N);
        // agg (in hA) = b + xw*dis^2, then scatter edges
        k_self_init<<<nb_NF4, 256, 0, stream>>>(xw, dis, b, hA, N);
        k_edge_scatter<<<nb_EF4, 256, 0, stream>>>(src, dst, dis, xw, hA, E);
        // relu; last layer writes d_out
        float* out = (layer == 2) ? (float*)d_out : hA;
        k_relu<<<nb_n4, 256, 0, stream>>>(hA, out, n4);
    }
}

// Round 2
// 366.757 us; speedup vs baseline: 9.0816x; 9.0816x over previous
//
#include <hip/hip_runtime.h>
#include <hip/hip_bf16.h>

// GCN encoder: h = relu(Agg(h @ W)) x3 after input linear.
// N=20000 nodes, E=640000 edges, H=128.
// Round 1 -> 2: replace atomic scatter (atomics write-through to HBM at 64B/line,
// 1.43GB & 1053us per layer) with CSR pull-aggregation (no atomics, gathers hit L2/LLC).
// ws layout: [dis: N f][off: N i][csr: E i][hA: N*128 f][xw: N*128 f]

#define HDIM 128

__global__ __launch_bounds__(256) void k_zero(int* __restrict__ off, int N) {
    int i = blockIdx.x * 256 + threadIdx.x;
    if (i < N) off[i] = 0;
}

__global__ __launch_bounds__(256) void k_count(const int* __restrict__ dst,
                                               int* __restrict__ off, int E) {
    int e = blockIdx.x * 256 + threadIdx.x;
    if (e < E) atomicAdd(&off[dst[e]], 1);
}

// Exclusive prefix-sum of off[] (in place) + dis = rsqrt(deg+1). Single block.
__global__ __launch_bounds__(256) void k_scan(int* __restrict__ off,
                                              float* __restrict__ dis, int N) {
    __shared__ int sums[256];
    int t = threadIdx.x;
    int chunk = (N + 255) >> 8;
    int lo = t * chunk;
    int hi = lo + chunk; if (hi > N) hi = N;
    int s = 0;
    for (int i = lo; i < hi; ++i) s += off[i];
    sums[t] = s;
    __syncthreads();
    if (t == 0) {
        int run = 0;
        for (int i = 0; i < 256; ++i) { int v = sums[i]; sums[i] = run; run += v; }
    }
    __syncthreads();
    int run = sums[t];
    for (int i = lo; i < hi; ++i) {
        int d = off[i];
        dis[i] = rsqrtf((float)(d + 1));   // +1 self-loop; deg>=1 always
        off[i] = run;
        run += d;
    }
}

// csr fill: pos = off[dst]++ ; csr[pos] = src. After this, off[v] = excl_prefix[v+1].
__global__ __launch_bounds__(256) void k_fill(const int* __restrict__ src,
                                              const int* __restrict__ dst,
                                              int* __restrict__ off,
                                              int* __restrict__ csr, int E) {
    int e = blockIdx.x * 256 + threadIdx.x;
    if (e >= E) return;
    int pos = atomicAdd(&off[dst[e]], 1);
    csr[pos] = src[e];
}

// out[N,128] = A[N,128] @ W[128,128] (+ b). W staged in LDS (64KB).
__global__ __launch_bounds__(256) void k_gemm(const float* __restrict__ A,
                                              const float* __restrict__ W,
                                              const float* __restrict__ b,
                                              float* __restrict__ out, int N) {
    __shared__ float Wl[HDIM * HDIM];
    __shared__ float Arow[8][HDIM];
    int tid = threadIdx.x;

    const float4* W4 = (const float4*)W;
    float4* Wl4 = (float4*)Wl;
    #pragma unroll
    for (int i = 0; i < 16; ++i) Wl4[tid + i * 256] = W4[tid + i * 256];

    int block_row = blockIdx.x * 8;
    {
        int r = tid >> 5, c = (tid & 31) * 4;
        int row = block_row + r;
        float4 v = make_float4(0.f, 0.f, 0.f, 0.f);
        if (row < N) v = *(const float4*)(A + (long long)row * HDIM + c);
        *(float4*)(&Arow[r][c]) = v;
    }
    __syncthreads();

    int rl = tid >> 5;
    int f4 = (tid & 31) * 4;
    float4 acc = b ? *(const float4*)(b + f4) : make_float4(0.f, 0.f, 0.f, 0.f);
    #pragma unroll 8
    for (int k = 0; k < HDIM; ++k) {
        float a = Arow[rl][k];
        float4 w = *(const float4*)(&Wl[k * HDIM + f4]);
        acc.x += a * w.x; acc.y += a * w.y; acc.z += a * w.z; acc.w += a * w.w;
    }
    int row = block_row + rl;
    if (row < N) *(float4*)(out + (long long)row * HDIM + f4) = acc;
}

// Pull aggregation, one wave64 per dst node; lane owns cols {lane, lane+64}.
// acc init = bias + self-loop term; relu fused at the end.
__global__ __launch_bounds__(256) void k_agg(const int* __restrict__ off,
                                             const int* __restrict__ csr,
                                             const float* __restrict__ dis,
                                             const float* __restrict__ xw,
                                             const float* __restrict__ b,
                                             float* __restrict__ out, int N) {
    int gid = blockIdx.x * 256 + threadIdx.x;
    int v = gid >> 6;
    if (v >= N) return;
    int lane = threadIdx.x & 63;

    int start = (v > 0) ? off[v - 1] : 0;   // off is post-fill: off[v] = excl[v+1]
    int end = off[v];
    float dv = dis[v];

    const float* xv = xw + (long long)v * HDIM;
    float acc0 = b[lane]      + xv[lane]      * dv * dv;
    float acc1 = b[lane + 64] + xv[lane + 64] * dv * dv;

    for (int i = start; i < end; i += 64) {
        int m = end - i; if (m > 64) m = 64;
        int   s_l = 0;
        float w_l = 0.f;
        if (lane < m) { s_l = csr[i + lane]; w_l = dis[s_l]; }
        for (int j = 0; j < m; ++j) {
            int   s = __shfl(s_l, j);
            float w = __shfl(w_l, j) * dv;
            const float* xs = xw + (long long)s * HDIM;
            acc0 += xs[lane]      * w;
            acc1 += xs[lane + 64] * w;
        }
    }
    float* ov = out + (long long)v * HDIM;
    ov[lane]      = fmaxf(acc0, 0.f);
    ov[lane + 64] = fmaxf(acc1, 0.f);
}

extern "C" void kernel_launch(void* const* d_in, const int* in_sizes, int n_in,
                              void* d_out, int out_size, void* d_ws, size_t ws_size,
                              hipStream_t stream) {
    const float* x    = (const float*)d_in[0];
    const int*   ei   = (const int*)d_in[1];   // [2, E]: first E = src, next E = dst
    const float* W_in = (const float*)d_in[2];
    const float* b_in = (const float*)d_in[3];
    const float* Ws   = (const float*)d_in[4]; // [3,128,128]
    const float* bs   = (const float*)d_in[5]; // [3,128]

    const int N = in_sizes[0] / HDIM;
    const int E = in_sizes[1] / 2;
    const int* src = ei;
    const int* dst = ei + E;

    float* dis = (float*)d_ws;                       // N floats
    int*   off = (int*)(dis + N);                    // N ints
    int*   csr = off + N;                            // E ints
    float* hA  = (float*)(csr + E);                  // N*128 floats (h / agg out)
    float* xw  = hA + (long long)N * HDIM;           // N*128 floats

    int nb_N    = (N + 255) / 256;
    int nb_E    = (E + 255) / 256;
    int nb_gemm = (N + 7) / 8;
    int nb_agg  = (N * 64 + 255) / 256;

    // CSR build + dis
    k_zero <<<nb_N, 256, 0, stream>>>(off, N);
    k_count<<<nb_E, 256, 0, stream>>>(dst, off, E);
    k_scan <<<1,    256, 0, stream>>>(off, dis, N);
    k_fill <<<nb_E, 256, 0, stream>>>(src, dst, off, csr, E);

    // h = x @ W_in + b_in
    k_gemm<<<nb_gemm, 256, 0, stream>>>(x, W_in, b_in, hA, N);

    for (int layer = 0; layer < 3; ++layer) {
        const float* W = Ws + (long long)layer * HDIM * HDIM;
        const float* b = bs + (long long)layer * HDIM;
        k_gemm<<<nb_gemm, 256, 0, stream>>>(hA, W, nullptr, xw, N);
        float* out = (layer == 2) ? (float*)d_out : hA;
        k_agg<<<nb_agg, 256, 0, stream>>>(off, csr, dis, xw, b, out, N);
    }
}

// Round 3
// 331.017 us; speedup vs baseline: 10.0621x; 1.1080x over previous
//
#include <hip/hip_runtime.h>
#include <hip/hip_bf16.h>

// GCN encoder: h = relu(Agg(h @ W)) x3 after input linear.
// N=20000 nodes, E=640000 edges, H=128.
// R1->R2: CSR pull-agg replaced atomics (3330->367us).
// R2->R3: GEMM rebuilt (64 rows/block, 4x4 reg tile, W staged once per 64 rows
//         instead of per 8 -> kills 160MB W restage); agg uses float2 lanes + 2-edge unroll.
// ws layout: [dis: N f][off: N i][csr: E i][hA: N*128 f][xw: N*128 f]

#define HDIM 128

__global__ __launch_bounds__(256) void k_zero(int* __restrict__ off, int N) {
    int i = blockIdx.x * 256 + threadIdx.x;
    if (i < N) off[i] = 0;
}

__global__ __launch_bounds__(256) void k_count(const int* __restrict__ dst,
                                               int* __restrict__ off, int E) {
    int e = blockIdx.x * 256 + threadIdx.x;
    if (e < E) atomicAdd(&off[dst[e]], 1);
}

// Exclusive prefix-sum of off[] (in place) + dis = rsqrt(deg+1). Single block.
__global__ __launch_bounds__(256) void k_scan(int* __restrict__ off,
                                              float* __restrict__ dis, int N) {
    __shared__ int sums[256];
    int t = threadIdx.x;
    int chunk = (N + 255) >> 8;
    int lo = t * chunk;
    int hi = lo + chunk; if (hi > N) hi = N;
    int s = 0;
    for (int i = lo; i < hi; ++i) s += off[i];
    sums[t] = s;
    __syncthreads();
    if (t == 0) {
        int run = 0;
        for (int i = 0; i < 256; ++i) { int v = sums[i]; sums[i] = run; run += v; }
    }
    __syncthreads();
    int run = sums[t];
    for (int i = lo; i < hi; ++i) {
        int d = off[i];
        dis[i] = rsqrtf((float)(d + 1));   // +1 self-loop; deg>=1 always
        off[i] = run;
        run += d;
    }
}

// csr fill: pos = off[dst]++ ; csr[pos] = src. After this, off[v] = excl_prefix[v+1].
__global__ __launch_bounds__(256) void k_fill(const int* __restrict__ src,
                                              const int* __restrict__ dst,
                                              int* __restrict__ off,
                                              int* __restrict__ csr, int E) {
    int e = blockIdx.x * 256 + threadIdx.x;
    if (e >= E) return;
    int pos = atomicAdd(&off[dst[e]], 1);
    csr[pos] = src[e];
}

// out[N,128] = A[N,128] @ W[128,128] (+ b).
// 512 threads, 64 rows/block. W (64KB) + A-tile (32KB) in LDS.
// Thread = 4 rows x 4 cols register tile; k unrolled by 4 with b128 LDS reads.
__global__ __launch_bounds__(512) void k_gemm(const float* __restrict__ A,
                                              const float* __restrict__ W,
                                              const float* __restrict__ b,
                                              float* __restrict__ out, int N) {
    __shared__ float Wl[HDIM * HDIM];     // 64KB
    __shared__ float At[64 * HDIM];       // 32KB
    int tid = threadIdx.x;
    int block_row = blockIdx.x * 64;

    // stage W: 4096 float4 / 512 threads = 8 each, coalesced
    {
        const float4* W4 = (const float4*)W;
        float4* Wl4 = (float4*)Wl;
        #pragma unroll
        for (int i = 0; i < 8; ++i) Wl4[tid + i * 512] = W4[tid + i * 512];
    }
    // stage A: 2048 float4 / 512 threads = 4 each, coalesced, zero-pad OOB rows
    {
        const float4* A4 = (const float4*)(A + (long long)block_row * HDIM);
        float4* At4 = (float4*)At;
        #pragma unroll
        for (int i = 0; i < 4; ++i) {
            int idx = tid + i * 512;          // float4 index; row = idx>>5
            float4 v = make_float4(0.f, 0.f, 0.f, 0.f);
            if (block_row + (idx >> 5) < N) v = A4[idx];
            At4[idx] = v;
        }
    }
    __syncthreads();

    int cc = tid & 31;          // float4 col group: cols cc*4..cc*4+3
    int rg = tid >> 5;          // 0..15: rows rg*4..rg*4+3
    const float* Arow0 = At + (rg * 4 + 0) * HDIM;
    const float* Arow1 = At + (rg * 4 + 1) * HDIM;
    const float* Arow2 = At + (rg * 4 + 2) * HDIM;
    const float* Arow3 = At + (rg * 4 + 3) * HDIM;

    float4 bb = b ? *(const float4*)(b + cc * 4) : make_float4(0.f, 0.f, 0.f, 0.f);
    float4 acc0 = bb, acc1 = bb, acc2 = bb, acc3 = bb;

    #pragma unroll 8
    for (int k = 0; k < HDIM; k += 4) {
        float4 a0 = *(const float4*)(Arow0 + k);
        float4 a1 = *(const float4*)(Arow1 + k);
        float4 a2 = *(const float4*)(Arow2 + k);
        float4 a3 = *(const float4*)(Arow3 + k);
        #pragma unroll
        for (int kk = 0; kk < 4; ++kk) {
            float4 w = *(const float4*)(&Wl[(k + kk) * HDIM + cc * 4]);
            float s0 = (&a0.x)[kk], s1 = (&a1.x)[kk], s2 = (&a2.x)[kk], s3 = (&a3.x)[kk];
            acc0.x += s0 * w.x; acc0.y += s0 * w.y; acc0.z += s0 * w.z; acc0.w += s0 * w.w;
            acc1.x += s1 * w.x; acc1.y += s1 * w.y; acc1.z += s1 * w.z; acc1.w += s1 * w.w;
            acc2.x += s2 * w.x; acc2.y += s2 * w.y; acc2.z += s2 * w.z; acc2.w += s2 * w.w;
            acc3.x += s3 * w.x; acc3.y += s3 * w.y; acc3.z += s3 * w.z; acc3.w += s3 * w.w;
        }
    }

    long long base = (long long)(block_row + rg * 4) * HDIM + cc * 4;
    if (block_row + rg * 4 + 0 < N) *(float4*)(out + base + 0 * HDIM) = acc0;
    if (block_row + rg * 4 + 1 < N) *(float4*)(out + base + 1 * HDIM) = acc1;
    if (block_row + rg * 4 + 2 < N) *(float4*)(out + base + 2 * HDIM) = acc2;
    if (block_row + rg * 4 + 3 < N) *(float4*)(out + base + 3 * HDIM) = acc3;
}

// Pull aggregation, one wave64 per dst node; lane owns cols {2*lane, 2*lane+1}
// (full 512B row per wave in one float2 load). Edge loop unrolled x2 for ILP.
// acc init = bias + self-loop term; relu fused.
__global__ __launch_bounds__(256) void k_agg(const int* __restrict__ off,
                                             const int* __restrict__ csr,
                                             const float* __restrict__ dis,
                                             const float* __restrict__ xw,
                                             const float* __restrict__ b,
                                             float* __restrict__ out, int N) {
    int gid = blockIdx.x * 256 + threadIdx.x;
    int v = gid >> 6;
    if (v >= N) return;
    int lane = threadIdx.x & 63;

    int start = (v > 0) ? off[v - 1] : 0;   // off is post-fill: off[v] = excl[v+1]
    int end = off[v];
    float dv = dis[v];

    const float2* xv = (const float2*)(xw + (long long)v * HDIM) + lane;
    float2 bb = *((const float2*)b + lane);
    float2 sv = *xv;
    float n = dv * dv;
    float accx = bb.x + sv.x * n;
    float accy = bb.y + sv.y * n;

    for (int i = start; i < end; i += 64) {
        int m = end - i; if (m > 64) m = 64;
        int   s_l = 0;
        float w_l = 0.f;
        if (lane < m) { s_l = csr[i + lane]; w_l = dis[s_l]; }
        int j = 0;
        for (; j + 1 < m; j += 2) {
            int   s0 = __shfl(s_l, j);
            int   s1 = __shfl(s_l, j + 1);
            float w0 = __shfl(w_l, j) * dv;
            float w1 = __shfl(w_l, j + 1) * dv;
            float2 x0 = *((const float2*)(xw + (long long)s0 * HDIM) + lane);
            float2 x1 = *((const float2*)(xw + (long long)s1 * HDIM) + lane);
            accx += x0.x * w0; accy += x0.y * w0;
            accx += x1.x * w1; accy += x1.y * w1;
        }
        if (j < m) {
            int   s0 = __shfl(s_l, j);
            float w0 = __shfl(w_l, j) * dv;
            float2 x0 = *((const float2*)(xw + (long long)s0 * HDIM) + lane);
            accx += x0.x * w0; accy += x0.y * w0;
        }
    }
    float2 o;
    o.x = fmaxf(accx, 0.f);
    o.y = fmaxf(accy, 0.f);
    *((float2*)(out + (long long)v * HDIM) + lane) = o;
}

extern "C" void kernel_launch(void* const* d_in, const int* in_sizes, int n_in,
                              void* d_out, int out_size, void* d_ws, size_t ws_size,
                              hipStream_t stream) {
    const float* x    = (const float*)d_in[0];
    const int*   ei   = (const int*)d_in[1];   // [2, E]: first E = src, next E = dst
    const float* W_in = (const float*)d_in[2];
    const float* b_in = (const float*)d_in[3];
    const float* Ws   = (const float*)d_in[4]; // [3,128,128]
    const float* bs   = (const float*)d_in[5]; // [3,128]

    const int N = in_sizes[0] / HDIM;
    const int E = in_sizes[1] / 2;
    const int* src = ei;
    const int* dst = ei + E;

    float* dis = (float*)d_ws;                       // N floats
    int*   off = (int*)(dis + N);                    // N ints
    int*   csr = off + N;                            // E ints
    float* hA  = (float*)(csr + E);                  // N*128 floats (h / agg out)
    float* xw  = hA + (long long)N * HDIM;           // N*128 floats

    int nb_N    = (N + 255) / 256;
    int nb_E    = (E + 255) / 256;
    int nb_gemm = (N + 63) / 64;
    int nb_agg  = (N * 64 + 255) / 256;

    // CSR build + dis
    k_zero <<<nb_N, 256, 0, stream>>>(off, N);
    k_count<<<nb_E, 256, 0, stream>>>(dst, off, E);
    k_scan <<<1,    256, 0, stream>>>(off, dis, N);
    k_fill <<<nb_E, 256, 0, stream>>>(src, dst, off, csr, E);

    // h = x @ W_in + b_in
    k_gemm<<<nb_gemm, 512, 0, stream>>>(x, W_in, b_in, hA, N);

    for (int layer = 0; layer < 3; ++layer) {
        const float* W = Ws + (long long)layer * HDIM * HDIM;
        const float* b = bs + (long long)layer * HDIM;
        k_gemm<<<nb_gemm, 512, 0, stream>>>(hA, W, nullptr, xw, N);
        float* out = (layer == 2) ? (float*)d_out : hA;
        k_agg<<<nb_agg, 256, 0, stream>>>(off, csr, dis, xw, b, out, N);
    }
}

// Round 4
// 273.948 us; speedup vs baseline: 12.1583x; 1.2083x over previous
//
#include <hip/hip_runtime.h>
#include <hip/hip_bf16.h>

// GCN encoder: h = relu(Agg(h @ W)) x3 after input linear.
// N=20000 nodes, E=640000 edges, H=128.
// R1->R2: CSR pull-agg replaced atomics (3330->367us).
// R2->R3: bigger GEMM tiles (367->331us).
// R3->R4: parallel scan (serial 1-block scan was 47us, top kernel);
//         GEMM 128rows/block 8x4 reg tile, grid=157=1 block/CU, LDS wall
//         (W-read bytes/FLOP halved) now ~4x under VALU wall.
// ws layout: [dis: N f][off: N i][csr: E i][hA: N*128 f][xw: N*128 f]
// (scan block-sums live in csr[0..19] until k_fill overwrites them)

#define HDIM 128
#define SCAN_TILE 1024

__global__ __launch_bounds__(256) void k_zero(int* __restrict__ off, int N) {
    int i = blockIdx.x * 256 + threadIdx.x;
    if (i < N) off[i] = 0;
}

__global__ __launch_bounds__(256) void k_count(const int* __restrict__ dst,
                                               int* __restrict__ off, int E) {
    int e = blockIdx.x * 256 + threadIdx.x;
    if (e < E) atomicAdd(&off[dst[e]], 1);
}

// Block-local exclusive scan of deg (in place) + dis = rsqrt(deg+1) + block sums.
// 20 blocks x 256 threads x 4 elements.
__global__ __launch_bounds__(256) void k_scan_blk(int* __restrict__ off,
                                                  float* __restrict__ dis,
                                                  int* __restrict__ bsum, int N) {
    int t = threadIdx.x;
    int base = blockIdx.x * SCAN_TILE + t * 4;
    int4 d = make_int4(0, 0, 0, 0);
    if (base + 3 < N) d = *(const int4*)(off + base);
    else {
        if (base + 0 < N) d.x = off[base + 0];
        if (base + 1 < N) d.y = off[base + 1];
        if (base + 2 < N) d.z = off[base + 2];
    }
    if (base + 0 < N) dis[base + 0] = rsqrtf((float)(d.x + 1));
    if (base + 1 < N) dis[base + 1] = rsqrtf((float)(d.y + 1));
    if (base + 2 < N) dis[base + 2] = rsqrtf((float)(d.z + 1));
    if (base + 3 < N) dis[base + 3] = rsqrtf((float)(d.w + 1));

    int tsum = d.x + d.y + d.z + d.w;
    int lane = t & 63;
    int incl = tsum;
    #pragma unroll
    for (int ofs = 1; ofs < 64; ofs <<= 1) {
        int u = __shfl_up(incl, ofs);
        if (lane >= ofs) incl += u;
    }
    __shared__ int wsum[4];
    if (lane == 63) wsum[t >> 6] = incl;
    __syncthreads();
    int w = t >> 6;
    int woff = 0;
    for (int i = 0; i < w; ++i) woff += wsum[i];

    int run = woff + incl - tsum;  // exclusive prefix (block-local)
    if (base + 0 < N) off[base + 0] = run; run += d.x;
    if (base + 1 < N) off[base + 1] = run; run += d.y;
    if (base + 2 < N) off[base + 2] = run; run += d.z;
    if (base + 3 < N) off[base + 3] = run;
    if (t == 255) bsum[blockIdx.x] = woff + incl;  // block total
}

// Add exclusive prefix of block sums to each block's elements.
__global__ __launch_bounds__(256) void k_scan_add(int* __restrict__ off,
                                                  const int* __restrict__ bsum, int N) {
    int bid = blockIdx.x;
    if (bid == 0) return;
    int p = 0;
    for (int i = 0; i < bid; ++i) p += bsum[i];
    int base = bid * SCAN_TILE + threadIdx.x * 4;
    if (base + 3 < N) {
        int4 v = *(const int4*)(off + base);
        v.x += p; v.y += p; v.z += p; v.w += p;
        *(int4*)(off + base) = v;
    } else {
        if (base + 0 < N) off[base + 0] += p;
        if (base + 1 < N) off[base + 1] += p;
        if (base + 2 < N) off[base + 2] += p;
    }
}

// csr fill: pos = off[dst]++ ; csr[pos] = src. After this, off[v] = excl_prefix[v+1].
__global__ __launch_bounds__(256) void k_fill(const int* __restrict__ src,
                                              const int* __restrict__ dst,
                                              int* __restrict__ off,
                                              int* __restrict__ csr, int E) {
    int e = blockIdx.x * 256 + threadIdx.x;
    if (e >= E) return;
    int pos = atomicAdd(&off[dst[e]], 1);
    csr[pos] = src[e];
}

// out[N,128] = A[N,128] @ W[128,128] (+ b).
// 512 threads, 128 rows/block (grid=157 -> 1 block/CU, no tail).
// Thread = 8 rows x 4 cols; W-LDS traffic 1MB per 16384 VALU-cyc -> LDS hidden.
__global__ __launch_bounds__(512) void k_gemm(const float* __restrict__ A,
                                              const float* __restrict__ W,
                                              const float* __restrict__ b,
                                              float* __restrict__ out, int N) {
    __shared__ float Wl[HDIM * HDIM];     // 64KB
    __shared__ float At[HDIM * HDIM];     // 64KB
    int tid = threadIdx.x;
    int block_row = blockIdx.x * HDIM;

    // stage W: 4096 float4 / 512 threads = 8 each, coalesced
    {
        const float4* W4 = (const float4*)W;
        float4* Wl4 = (float4*)Wl;
        #pragma unroll
        for (int i = 0; i < 8; ++i) Wl4[tid + i * 512] = W4[tid + i * 512];
    }
    // stage A: 4096 float4 / 512 threads = 8 each, zero-pad OOB rows
    {
        const float4* A4 = (const float4*)(A + (long long)block_row * HDIM);
        float4* At4 = (float4*)At;
        #pragma unroll
        for (int i = 0; i < 8; ++i) {
            int idx = tid + i * 512;          // float4 index; row = idx>>5
            float4 v = make_float4(0.f, 0.f, 0.f, 0.f);
            if (block_row + (idx >> 5) < N) v = A4[idx];
            At4[idx] = v;
        }
    }
    __syncthreads();

    int cc = tid & 31;          // cols cc*4..cc*4+3
    int rg = tid >> 5;          // 0..15: rows rg*8..rg*8+7
    const float* Ar = At + rg * 8 * HDIM;

    float4 bb = b ? *(const float4*)(b + cc * 4) : make_float4(0.f, 0.f, 0.f, 0.f);
    float4 acc[8];
    #pragma unroll
    for (int r = 0; r < 8; ++r) acc[r] = bb;

    #pragma unroll 4
    for (int k = 0; k < HDIM; k += 4) {
        float4 w0 = *(const float4*)(&Wl[(k + 0) * HDIM + cc * 4]);
        float4 w1 = *(const float4*)(&Wl[(k + 1) * HDIM + cc * 4]);
        float4 w2 = *(const float4*)(&Wl[(k + 2) * HDIM + cc * 4]);
        float4 w3 = *(const float4*)(&Wl[(k + 3) * HDIM + cc * 4]);
        #pragma unroll
        for (int r = 0; r < 8; ++r) {
            float4 a = *(const float4*)(Ar + r * HDIM + k);
            acc[r].x += a.x * w0.x; acc[r].y += a.x * w0.y;
            acc[r].z += a.x * w0.z; acc[r].w += a.x * w0.w;
            acc[r].x += a.y * w1.x; acc[r].y += a.y * w1.y;
            acc[r].z += a.y * w1.z; acc[r].w += a.y * w1.w;
            acc[r].x += a.z * w2.x; acc[r].y += a.z * w2.y;
            acc[r].z += a.z * w2.z; acc[r].w += a.z * w2.w;
            acc[r].x += a.w * w3.x; acc[r].y += a.w * w3.y;
            acc[r].z += a.w * w3.z; acc[r].w += a.w * w3.w;
        }
    }

    int r0 = block_row + rg * 8;
    #pragma unroll
    for (int r = 0; r < 8; ++r)
        if (r0 + r < N)
            *(float4*)(out + (long long)(r0 + r) * HDIM + cc * 4) = acc[r];
}

// Pull aggregation, one wave64 per dst node; lane owns cols {2*lane, 2*lane+1}.
__global__ __launch_bounds__(256) void k_agg(const int* __restrict__ off,
                                             const int* __restrict__ csr,
                                             const float* __restrict__ dis,
                                             const float* __restrict__ xw,
                                             const float* __restrict__ b,
                                             float* __restrict__ out, int N) {
    int gid = blockIdx.x * 256 + threadIdx.x;
    int v = gid >> 6;
    if (v >= N) return;
    int lane = threadIdx.x & 63;

    int start = (v > 0) ? off[v - 1] : 0;   // off is post-fill: off[v] = excl[v+1]
    int end = off[v];
    float dv = dis[v];

    const float2* xv = (const float2*)(xw + (long long)v * HDIM) + lane;
    float2 bb = *((const float2*)b + lane);
    float2 sv = *xv;
    float n = dv * dv;
    float accx = bb.x + sv.x * n;
    float accy = bb.y + sv.y * n;

    for (int i = start; i < end; i += 64) {
        int m = end - i; if (m > 64) m = 64;
        int   s_l = 0;
        float w_l = 0.f;
        if (lane < m) { s_l = csr[i + lane]; w_l = dis[s_l]; }
        int j = 0;
        for (; j + 1 < m; j += 2) {
            int   s0 = __shfl(s_l, j);
            int   s1 = __shfl(s_l, j + 1);
            float w0 = __shfl(w_l, j) * dv;
            float w1 = __shfl(w_l, j + 1) * dv;
            float2 x0 = *((const float2*)(xw + (long long)s0 * HDIM) + lane);
            float2 x1 = *((const float2*)(xw + (long long)s1 * HDIM) + lane);
            accx += x0.x * w0; accy += x0.y * w0;
            accx += x1.x * w1; accy += x1.y * w1;
        }
        if (j < m) {
            int   s0 = __shfl(s_l, j);
            float w0 = __shfl(w_l, j) * dv;
            float2 x0 = *((const float2*)(xw + (long long)s0 * HDIM) + lane);
            accx += x0.x * w0; accy += x0.y * w0;
        }
    }
    float2 o;
    o.x = fmaxf(accx, 0.f);
    o.y = fmaxf(accy, 0.f);
    *((float2*)(out + (long long)v * HDIM) + lane) = o;
}

extern "C" void kernel_launch(void* const* d_in, const int* in_sizes, int n_in,
                              void* d_out, int out_size, void* d_ws, size_t ws_size,
                              hipStream_t stream) {
    const float* x    = (const float*)d_in[0];
    const int*   ei   = (const int*)d_in[1];   // [2, E]: first E = src, next E = dst
    const float* W_in = (const float*)d_in[2];
    const float* b_in = (const float*)d_in[3];
    const float* Ws   = (const float*)d_in[4]; // [3,128,128]
    const float* bs   = (const float*)d_in[5]; // [3,128]

    const int N = in_sizes[0] / HDIM;
    const int E = in_sizes[1] / 2;
    const int* src = ei;
    const int* dst = ei + E;

    float* dis = (float*)d_ws;                       // N floats
    int*   off = (int*)(dis + N);                    // N ints
    int*   csr = off + N;                            // E ints (first 32 = scan bsums, transient)
    float* hA  = (float*)(csr + E);                  // N*128 floats (h / agg out)
    float* xw  = hA + (long long)N * HDIM;           // N*128 floats

    int nb_N    = (N + 255) / 256;
    int nb_E    = (E + 255) / 256;
    int nb_scan = (N + SCAN_TILE - 1) / SCAN_TILE;
    int nb_gemm = (N + HDIM - 1) / HDIM;
    int nb_agg  = (N * 64 + 255) / 256;

    // CSR build + dis
    k_zero    <<<nb_N,    256, 0, stream>>>(off, N);
    k_count   <<<nb_E,    256, 0, stream>>>(dst, off, E);
    k_scan_blk<<<nb_scan, 256, 0, stream>>>(off, dis, csr, N);
    k_scan_add<<<nb_scan, 256, 0, stream>>>(off, csr, N);
    k_fill    <<<nb_E,    256, 0, stream>>>(src, dst, off, csr, E);

    // h = x @ W_in + b_in
    k_gemm<<<nb_gemm, 512, 0, stream>>>(x, W_in, b_in, hA, N);

    for (int layer = 0; layer < 3; ++layer) {
        const float* W = Ws + (long long)layer * HDIM * HDIM;
        const float* b = bs + (long long)layer * HDIM;
        k_gemm<<<nb_gemm, 512, 0, stream>>>(hA, W, nullptr, xw, N);
        float* out = (layer == 2) ? (float*)d_out : hA;
        k_agg<<<nb_agg, 256, 0, stream>>>(off, csr, dis, xw, b, out, N);
    }
}